// Round 14
// baseline (19593.373 us; speedup 1.0000x reference)
//
#include <hip/hip_runtime.h>
#include <hip/hip_bf16.h>

#define T_STEPS 256
#define BS      64
#define NTOKEN  512
#define NINP    512
#define NHID    2048
#define NB      8
#define TOPKN   4
#define BSZ     256
#define ATT_OUT 340
#define DK      64
#define NH_C    4
#define DK_C    32
#define KSUM    (ATT_OUT + BSZ)   // 596
#define KV1     (DK + ATT_OUT)    // 404
#define RV      596               // k1v1 row: [v1 0..340) [wk 340..596), wk is BSZ-dim
#define GATES   1024
#define NWG     256

#define AGENT __HIP_MEMORY_SCOPE_AGENT

__device__ __forceinline__ float sigf(float x) { return 1.0f / (1.0f + expf(-x)); }
__device__ __forceinline__ float aload(const float* p) {
  return __hip_atomic_load(p, __ATOMIC_RELAXED, AGENT);
}
__device__ __forceinline__ void astore(float* p, float v) {
  __hip_atomic_store(p, v, __ATOMIC_RELAXED, AGENT);
}
__device__ __forceinline__ unsigned aloadu(const unsigned* p) {
  return __hip_atomic_load(p, __ATOMIC_RELAXED, AGENT);
}
__device__ __forceinline__ void astoreu(unsigned* p, unsigned v) {
  __hip_atomic_store(p, v, __ATOMIC_RELAXED, AGENT);
}

__device__ __forceinline__ void gfma(float4& acc, const float4& a4, const float4& w0,
                                     const float4& w1, const float4& w2, const float4& w3) {
  acc.x += a4.x * w0.x + a4.y * w1.x + a4.z * w2.x + a4.w * w3.x;
  acc.y += a4.x * w0.y + a4.y * w1.y + a4.z * w2.y + a4.w * w3.y;
  acc.z += a4.x * w0.z + a4.y * w1.z + a4.z * w2.z + a4.w * w3.z;
  acc.w += a4.x * w0.w + a4.y * w1.w + a4.z * w2.w + a4.w * w3.w;
}
__device__ __forceinline__ void sfma(float4& acc, float s, const float4& w) {
  acc.x += s * w.x; acc.y += s * w.y; acc.z += s * w.z; acc.w += s * w.w;
}

// Distributed-arrival grid barrier; release via 8 per-XCD shared gen lines
// (R6-measured fast path: hot, constantly-polled lines).
__device__ __forceinline__ void gbar(unsigned* flags, unsigned* gen, unsigned e) {
  const int w = blockIdx.x, tid = threadIdx.x;
  asm volatile("s_waitcnt vmcnt(0) lgkmcnt(0)" ::: "memory");
  __syncthreads();
  if (tid == 0) astoreu(&flags[w * 16], e);
  if (w == NWG - 1) {
    if (tid < NWG) {
      while (aloadu(&flags[tid * 16]) < e) __builtin_amdgcn_s_sleep(1);
    }
    __syncthreads();
    if (tid < 8) astoreu(&gen[tid * 16], e);
  } else {
    if (tid == 0) {
      while (aloadu(&gen[(w & 7) * 16]) < e) __builtin_amdgcn_s_sleep(1);
    }
  }
  __syncthreads();
}

// ---------- Precompute 1: Wc = W_enc @ [Wk | Wv], bias_kv = b_enc @ [Wk|Wv]
__global__ void k_wc(const float* __restrict__ W_enc, const float* __restrict__ b_enc,
                     const float* __restrict__ Wk, const float* __restrict__ Wv,
                     float* __restrict__ Wc, float* __restrict__ bias_kv) {
  __shared__ float row[NINP];
  int d = blockIdx.x;
  const float* src = (d < NTOKEN) ? (W_enc + (size_t)d * NINP) : b_enc;
  for (int i = threadIdx.x; i < NINP; i += blockDim.x) row[i] = src[i];
  __syncthreads();
  float* dst = (d < NTOKEN) ? (Wc + (size_t)d * KV1) : bias_kv;
  for (int j = threadIdx.x; j < KV1; j += blockDim.x) {
    float acc = 0.f;
    if (j < DK) {
      for (int p = 0; p < NINP; ++p) acc += row[p] * Wk[(size_t)p * DK + j];
    } else {
      int jj = j - DK;
      for (int p = 0; p < NINP; ++p) acc += row[p] * Wv[(size_t)p * ATT_OUT + jj];
    }
    dst[j] = acc;
  }
}

// ---------- Precompute 2: k1v1[t,b] = [v1 | wk],  wk = Wq @ k1 (BSZ components)
__global__ void k_kv(const float* __restrict__ x, const float* __restrict__ Wc,
                     const float* __restrict__ bias_kv, const float* __restrict__ Wq,
                     float* __restrict__ k1v1) {
  __shared__ float xl[8 * NTOKEN];
  __shared__ float k1s[8 * DK];
  int r0 = blockIdx.x * 8;
  for (int i = threadIdx.x; i < 8 * NTOKEN; i += blockDim.x)
    xl[i] = x[(size_t)r0 * NTOKEN + i];
  __syncthreads();
  for (int j = threadIdx.x; j < KV1; j += 256) {
    float bj = bias_kv[j];
    float acc[8];
#pragma unroll
    for (int r = 0; r < 8; ++r) acc[r] = bj;
    for (int d = 0; d < NTOKEN; ++d) {
      float wc = Wc[(size_t)d * KV1 + j];
#pragma unroll
      for (int r = 0; r < 8; ++r) acc[r] += xl[r * NTOKEN + d] * wc;
    }
    if (j < DK) {
#pragma unroll
      for (int r = 0; r < 8; ++r) k1s[r * DK + j] = acc[r];
    } else {
#pragma unroll
      for (int r = 0; r < 8; ++r) k1v1[(size_t)(r0 + r) * RV + (j - DK)] = acc[r];
    }
  }
  __syncthreads();
  {  // wk[r][d] = sum_dk k1[r][dk] * Wq[d][dk],  d = threadIdx.x in [0,256)
    int d = threadIdx.x;
    float a[8];
#pragma unroll
    for (int r = 0; r < 8; ++r) a[r] = 0.f;
    for (int dk4 = 0; dk4 < 16; ++dk4) {
      float4 w4 = *(const float4*)&Wq[(size_t)d * DK + dk4 * 4];
#pragma unroll
      for (int r = 0; r < 8; ++r) {
        float4 kk = *(const float4*)&k1s[r * DK + dk4 * 4];
        a[r] += kk.x * w4.x + kk.y * w4.y + kk.z * w4.z + kk.w * w4.w;
      }
    }
#pragma unroll
    for (int r = 0; r < 8; ++r) k1v1[(size_t)(r0 + r) * RV + ATT_OUT + d] = a[r];
  }
}

// ---------- Precompute 3: gate-interleaved fused weights
__global__ void k_fuse(const float* __restrict__ Wi, const float* __restrict__ Wh,
                       const float* __restrict__ b_lstm,
                       float* __restrict__ Wf, float* __restrict__ bf) {
  int nk = blockIdx.x;  // 8*596
  int n = nk / KSUM, k = nk % KSUM;
  const float* src = (k < ATT_OUT) ? (Wi + ((size_t)n * ATT_OUT + k) * GATES)
                                   : (Wh + ((size_t)n * BSZ + (k - ATT_OUT)) * GATES);
  float* dst = Wf + ((size_t)n * KSUM + k) * GATES;
  for (int gc = threadIdx.x; gc < GATES; gc += blockDim.x) {
    int t = gc >> 8, j = gc & 255;
    dst[j * 4 + t] = src[gc];
  }
  if (k == 0) {
    for (int gc = threadIdx.x; gc < GATES; gc += blockDim.x) {
      int t = gc >> 8, j = gc & 255;
      bf[(size_t)n * GATES + j * 4 + t] = b_lstm[(size_t)n * GATES + gc];
    }
  }
}

// ---------- Main persistent RNN kernel: 256 WGs x 1024 threads
// R13 structure (unified Al, acc[8], no spills) + R6 barrier release +
// issue-early S1 prefetch of wk4/v1 (dead before GEMM).
// LDS (floats): c_cur[512]@0 c_pend[512]@512 zl[128]@1024 attl[16]@1152
//   h_comm[2048]@1168  Al[16][600]@3216.  red4/B-phase overlay dead Al.
__global__ __launch_bounds__(1024)
void k_rnn(const float* __restrict__ k1v1, const float* __restrict__ Wf,
           const float* __restrict__ bf,
           const float* __restrict__ Wq_c, const float* __restrict__ Wk_c,
           const float* __restrict__ Wv_c, const float* __restrict__ Wo_c,
           const float* __restrict__ c0,
           float* h, float* hnew, float* zbuf,
           unsigned* bar, float* __restrict__ out) {
  const int w   = blockIdx.x;       // w = bg*64 + csg*8 + n
  const int tid = threadIdx.x;      // 1024
  const int n   = w & 7;            // block -> XCD, Wf[n] L2-resident
  const int csg = (w >> 3) & 7;     // 32-cell slice
  const int bg  = w >> 6;           // batch group of 16
  const int jjG = tid & 31, boG = (tid >> 5) & 1, khG = tid >> 6;
  const int bb  = tid >> 6, lane = tid & 63;   // staging roles
  // S3 prefetch coordinates (i0 = tid, i1 = tid + 1024)
  const int pb0 = tid / 85, pq0 = tid - pb0 * 85;
  const int i1  = tid + 1024;
  const int pb1 = i1 / 85, pq1 = i1 - pb1 * 85;  // valid iff i1 < 1360

  unsigned* flags = bar;
  unsigned* gen   = bar + 4096;

  __shared__ __align__(16) float smem[12816];
  float* c_cur  = smem;            // [16][32]
  float* c_pend = smem + 512;      // [16][32]
  float* zl     = smem + 1024;     // [16][8]
  float* attl   = smem + 1152;     // [16]
  float* h_comm = smem + 1168;     // [2048] (w<64 only)
  float* Al     = smem + 3216;     // [16][600]: [0,340)=att*v1, [340,596)=h

  // ===== init =====
  if (tid < 512)
    c_cur[tid] = c0[(size_t)(bg * 16 + (tid >> 5)) * NHID + n * BSZ + csg * 32 + (tid & 31)];
  if (w < BS) {
#pragma unroll
    for (int r = 0; r < 2; ++r) {
      int i = r * 1024 + tid;
      h_comm[i] = aload(&h[(size_t)w * NHID + i]);
    }
  }

  for (int t = 0; t < T_STEPS; ++t) {
    float* zwr = zbuf + (t & 1) * 512;        // z(t)
    float* zrd = zbuf + ((t & 1) ^ 1) * 512;  // z(t-1)
    const size_t rowb = (size_t)t * BS + bg * 16;

    // ===== S1: issue ALL step-t loads concurrently, stage h -> Al =====
    // prefetch wk (for S2) and v1 (for S3); dead before the GEMM
    float4 wk4 = *(const float4*)&k1v1[(rowb + bb) * RV + ATT_OUT + lane * 4];
    float4 pv0 = *(const float4*)&k1v1[(rowb + pb0) * RV + pq0 * 4];
    float4 pv1;
    if (i1 < 1360) pv1 = *(const float4*)&k1v1[(rowb + pb1) * RV + pq1 * 4];
    if (tid >= 512 && tid < 640) {
      int q = tid - 512;
      zl[q] = aload(&zrd[(bg * 16 + (q >> 3)) * 8 + (q & 7)]);
    }
#pragma unroll
    for (int r = 0; r < 4; ++r) {
      int i = r * 1024 + tid;
      int bb2 = i >> 8, d = i & 255;
      Al[bb2 * 600 + ATT_OUT + d] = aload(&h[(size_t)(bg * 16 + bb2) * NHID + n * BSZ + d]);
    }
    __syncthreads();
    // ===== S2: z = (h . wk)/8 per (batch=wave), wk from registers =====
    {
      float4 h4 = *(float4*)&Al[bb * 600 + ATT_OUT + lane * 4];
      float zp = h4.x * wk4.x + h4.y * wk4.y + h4.z * wk4.z + h4.w * wk4.w;
      zp += __shfl_xor(zp, 1);  zp += __shfl_xor(zp, 2);  zp += __shfl_xor(zp, 4);
      zp += __shfl_xor(zp, 8);  zp += __shfl_xor(zp, 16); zp += __shfl_xor(zp, 32);
      if (lane == 0) {
        float z = zp * 0.125f;
        attl[bb] = sigf(z);
        if (csg == 0) astore(&zwr[(bg * 16 + bb) * 8 + n], z);
      }
    }
    __syncthreads();
    // ===== S3: Al rows [0,340) = att1 * v1 (from prefetch registers) =====
    {
      float a0 = attl[pb0];
      float4 r0;
      r0.x = a0 * pv0.x; r0.y = a0 * pv0.y; r0.z = a0 * pv0.z; r0.w = a0 * pv0.w;
      *(float4*)&Al[pb0 * 600 + pq0 * 4] = r0;
      if (i1 < 1360) {
        float a1 = attl[pb1];
        float4 r1;
        r1.x = a1 * pv1.x; r1.y = a1 * pv1.y; r1.z = a1 * pv1.z; r1.w = a1 * pv1.w;
        *(float4*)&Al[pb1 * 600 + pq1 * 4] = r1;
      }
    }
    __syncthreads();

    // ===== S4: GEMM — thread (khG16, boG2, jjG32): 8 batches x 4 gates =====
    float4 acc[8];
#pragma unroll
    for (int i = 0; i < 8; ++i) acc[i] = make_float4(0.f, 0.f, 0.f, 0.f);
    {
      const float* Wr = Wf + (size_t)n * KSUM * GATES + (size_t)(csg * 32 + jjG) * 4;
      const float* Ab = Al + boG * 8 * 600;
#pragma unroll 2
      for (int k4 = khG * 4; k4 < KSUM; k4 += 64) {
        const float* wp = Wr + (size_t)k4 * GATES;
        float4 w0 = *(const float4*)(wp);
        float4 w1 = *(const float4*)(wp + GATES);
        float4 w2 = *(const float4*)(wp + 2 * GATES);
        float4 w3 = *(const float4*)(wp + 3 * GATES);
#pragma unroll
        for (int i = 0; i < 8; ++i) {
          float4 a4 = *(const float4*)&Ab[i * 600 + k4];
          gfma(acc[i], a4, w0, w1, w2, w3);
        }
      }
    }
    __syncthreads();  // Al reads done; red4 overlays it

    // ===== S5: deterministic 4-pass kh-reduction + LSTM + lazy c-commit =====
    {
      float4* red4 = (float4*)Al;
#pragma unroll
      for (int p = 0; p < 4; ++p) {
        red4[khG * 132 + boG * 64 + jjG * 2 + 0] = acc[2 * p];
        red4[khG * 132 + boG * 64 + jjG * 2 + 1] = acc[2 * p + 1];
        __syncthreads();
        if (tid < 128) {
          const int rb = tid >> 5, jjr = tid & 31;
          const int bo_r = rb >> 1, q_r = rb & 1;
          const int batch = bo_r * 8 + 2 * p + q_r;
          float4 g4 = make_float4(0.f, 0.f, 0.f, 0.f);
#pragma unroll
          for (int kh = 0; kh < 16; ++kh) {   // fixed order -> deterministic
            float4 v = red4[kh * 132 + bo_r * 64 + jjr * 2 + q_r];
            g4.x += v.x; g4.y += v.y; g4.z += v.z; g4.w += v.w;
          }
          const int jgr = csg * 32 + jjr;
          float4 bia = *(const float4*)&bf[(size_t)n * GATES + jgr * 4];
          float ig = sigf(g4.x + bia.x), fg = sigf(g4.y + bia.y);
          float gg = tanhf(g4.z + bia.z), og = sigf(g4.w + bia.w);
          float cc = c_cur[batch * 32 + jjr];
          if (t > 0) {
            float zn = zl[batch * 8 + n];
            int rank = 0;
#pragma unroll
            for (int j = 0; j < NB; ++j) {
              float zj = zl[batch * 8 + j];
              rank += (zj > zn || (zj == zn && j < n)) ? 1 : 0;
            }
            if (rank < TOPKN) cc = c_pend[batch * 32 + jjr];
          }
          float cn = fg * cc + ig * gg;
          float hn = og * tanhf(cn);
          c_cur[batch * 32 + jjr]  = cc;
          c_pend[batch * 32 + jjr] = cn;
          astore(&hnew[(size_t)(bg * 16 + batch) * NHID + n * BSZ + jgr], hn);
        }
        __syncthreads();
      }
    }
    gbar(flags, gen, 2u * t + 1u);

    // ===== PHASE B (WGs 0..63, one batch each) =====
    if (w < BS) {
      const int b = w;
      float* hnewl = Al;
      float* qcl   = Al + 2048;
      float* kcl   = Al + 3072;
      float* vcl   = Al + 4096;
      float* ocl   = Al + 5120;
      float* scl   = Al + 6144;   // [4][8][8]
      float* acl   = Al + 6400;   // [4][8][8]
      float* zlB   = Al + 6656;   // [8]

      for (int i = tid; i < NHID; i += 1024)
        hnewl[i] = aload(&hnew[(size_t)b * NHID + i]);
      if (tid >= 1016) zlB[tid - 1016] = aload(&zwr[b * 8 + (tid - 1016)]);
      __syncthreads();
      // qkv: tid<768 : (mat3, c4 32, kq 8) -> 8 nn accumulators, kq shfl-reduce
      if (tid < 768) {
        int mat = tid >> 8, c4 = (tid >> 3) & 31, kq = tid & 7;
        int c0 = c4 * 4;
        const float* W = (mat == 0) ? Wq_c : (mat == 1) ? Wk_c : Wv_c;
        float4 a8[8];
#pragma unroll
        for (int i = 0; i < 8; ++i) a8[i] = make_float4(0.f, 0.f, 0.f, 0.f);
#pragma unroll 2
        for (int m = 0; m < 8; ++m) {
          int d0 = kq * 4 + 32 * m;
          float4 w_0 = *(const float4*)&W[(size_t)(d0 + 0) * 128 + c0];
          float4 w_1 = *(const float4*)&W[(size_t)(d0 + 1) * 128 + c0];
          float4 w_2 = *(const float4*)&W[(size_t)(d0 + 2) * 128 + c0];
          float4 w_3 = *(const float4*)&W[(size_t)(d0 + 3) * 128 + c0];
#pragma unroll
          for (int nn = 0; nn < 8; ++nn) {
            float4 h4 = *(const float4*)&hnewl[nn * 256 + d0];
            sfma(a8[nn], h4.x, w_0); sfma(a8[nn], h4.y, w_1);
            sfma(a8[nn], h4.z, w_2); sfma(a8[nn], h4.w, w_3);
          }
        }
#pragma unroll
        for (int mk = 1; mk <= 4; mk <<= 1) {
#pragma unroll
          for (int nn = 0; nn < 8; ++nn) {
            a8[nn].x += __shfl_xor(a8[nn].x, mk);
            a8[nn].y += __shfl_xor(a8[nn].y, mk);
            a8[nn].z += __shfl_xor(a8[nn].z, mk);
            a8[nn].w += __shfl_xor(a8[nn].w, mk);
          }
        }
        if (kq == 0) {
          float* dst = (mat == 0) ? qcl : (mat == 1) ? kcl : vcl;
#pragma unroll
          for (int nn = 0; nn < 8; ++nn)
            *(float4*)&dst[nn * 128 + c0] = a8[nn];
        }
      }
      __syncthreads();
      // scores: tid<256 : (hh, nq, m) dot32
      if (tid < 256) {
        int hh = tid >> 6, nq = (tid >> 3) & 7, m = tid & 7;
        const float* qrow = &qcl[nq * 128 + hh * 32];
        const float* krow = &kcl[m * 128 + hh * 32];
        float a = 0.f;
#pragma unroll
        for (int k4 = 0; k4 < 8; ++k4) {
          float4 q4 = *(const float4*)&qrow[k4 * 4];
          float4 kv = *(const float4*)&krow[k4 * 4];
          a += q4.x * kv.x + q4.y * kv.y + q4.z * kv.z + q4.w * kv.w;
        }
        scl[tid] = a * 0.17677669529663687f;
      }
      __syncthreads();
      if (tid < 32) {  // softmax rows
        int hh = tid >> 3, nq = tid & 7;
        const float* row = &scl[hh * 64 + nq * 8];
        float mx = -1e30f;
#pragma unroll
        for (int m = 0; m < NB; ++m) mx = fmaxf(mx, row[m]);
        float e[NB]; float sum = 0.f;
#pragma unroll
        for (int m = 0; m < NB; ++m) { e[m] = expf(row[m] - mx); sum += e[m]; }
        float inv = 1.f / sum;
#pragma unroll
        for (int m = 0; m < NB; ++m) acl[(hh * 8 + nq) * 8 + m] = e[m] * inv;
      }
      __syncthreads();
      if (tid < 256) {  // oc = ac @ vc
        int nn = tid >> 5, c4 = tid & 31, c0 = c4 * 4, hh = c4 >> 3;
        const float* arow = &acl[(hh * 8 + nn) * 8];
        float4 a4 = make_float4(0.f, 0.f, 0.f, 0.f);
#pragma unroll
        for (int m = 0; m < NB; ++m) {
          float a = arow[m];
          float4 v4 = *(const float4*)&vcl[m * 128 + c0];
          sfma(a4, a, v4);
        }
        *(float4*)&ocl[tid * 4] = a4;
      }
      __syncthreads();
      if (tid < 512) {  // commit h (h_comm + global h for masked) + out
        int nn = tid >> 6, j0 = (tid & 63) * 4;
        int li = nn * BSZ + j0;
        float zn = zlB[nn];
        int rank = 0;
#pragma unroll
        for (int j = 0; j < NB; ++j) {
          float zj = zlB[j];
          rank += (zj > zn || (zj == zn && j < nn)) ? 1 : 0;
        }
        float4 hv4;
        if (rank < TOPKN) {
          const float* oc = &ocl[nn * 128];
          float4 add = make_float4(0.f, 0.f, 0.f, 0.f);
#pragma unroll 4
          for (int p = 0; p < 128; ++p) {
            float o = oc[p];
            float4 w4 = *(const float4*)&Wo_c[(size_t)p * BSZ + j0];
            sfma(add, o, w4);
          }
          hv4.x = hnewl[li] + add.x;     hv4.y = hnewl[li + 1] + add.y;
          hv4.z = hnewl[li + 2] + add.z; hv4.w = hnewl[li + 3] + add.w;
          *(float4*)&h_comm[li] = hv4;
          size_t base = (size_t)b * NHID + li;
          astore(&h[base], hv4.x);     astore(&h[base + 1], hv4.y);
          astore(&h[base + 2], hv4.z); astore(&h[base + 3], hv4.w);
        } else {
          hv4 = *(float4*)&h_comm[li];
        }
        *(float4*)&out[((size_t)t * BS + b) * NHID + li] = hv4;
      }
    }
    gbar(flags, gen, 2u * t + 2u);
  }
}

__global__ void k_sentinel(float* out) { out[0] = 12345.0f; }

extern "C" void kernel_launch(void* const* d_in, const int* in_sizes, int n_in,
                              void* d_out, int out_size, void* d_ws, size_t ws_size,
                              hipStream_t stream) {
  (void)in_sizes; (void)n_in; (void)out_size;
  const float* x      = (const float*)d_in[0];
  const float* h0     = (const float*)d_in[1];
  const float* c0     = (const float*)d_in[2];
  const float* W_enc  = (const float*)d_in[3];
  const float* b_enc  = (const float*)d_in[4];
  const float* Wq     = (const float*)d_in[5];
  const float* Wk     = (const float*)d_in[6];
  const float* Wv     = (const float*)d_in[7];
  const float* Wi     = (const float*)d_in[8];
  const float* Wh     = (const float*)d_in[9];
  const float* b_lstm = (const float*)d_in[10];
  const float* Wq_c   = (const float*)d_in[11];
  const float* Wk_c   = (const float*)d_in[12];
  const float* Wv_c   = (const float*)d_in[13];
  const float* Wo_c   = (const float*)d_in[14];
  float* out = (float*)d_out;

  float* ws = (float*)d_ws;
  size_t off = 0;
  auto alloc = [&](size_t nf) { float* p = ws + off; off += (nf + 15) & ~(size_t)15; return p; };
  float* k1v1 = alloc((size_t)T_STEPS * BS * RV);
  float* Wc   = alloc((size_t)NTOKEN * KV1);
  float* bias = alloc(KV1);
  float* Wf   = alloc((size_t)NB * KSUM * GATES);
  float* bf   = alloc((size_t)NB * GATES);
  float* h    = alloc((size_t)BS * NHID);
  float* hnew = alloc((size_t)BS * NHID);
  float* zbuf = alloc(2 * (size_t)BS * NB);
  // barrier: 256 flag lines + 8 gen lines (16 u32 each)
  unsigned* bar = (unsigned*)(ws + off); off += 8192 + 16;

  if (ws_size < off * sizeof(float)) {  // loud failure instead of OOB corruption
    hipLaunchKernelGGL(k_sentinel, dim3(1), dim3(1), 0, stream, out);
    return;
  }

  hipMemsetAsync(bar, 0, 8192 * sizeof(unsigned), stream);
  hipMemcpyAsync(h, h0, (size_t)BS * NHID * sizeof(float), hipMemcpyDeviceToDevice, stream);

  hipLaunchKernelGGL(k_wc,   dim3(NTOKEN + 1),       dim3(128), 0, stream, W_enc, b_enc, Wk, Wv, Wc, bias);
  hipLaunchKernelGGL(k_kv,   dim3(T_STEPS * BS / 8), dim3(256), 0, stream, x, Wc, bias, Wq, k1v1);
  hipLaunchKernelGGL(k_fuse, dim3(NB * KSUM),        dim3(256), 0, stream, Wi, Wh, b_lstm, Wf, bf);
  hipLaunchKernelGGL(k_rnn,  dim3(NWG),              dim3(1024), 0, stream,
                     k1v1, Wf, bf, Wq_c, Wk_c, Wv_c, Wo_c, c0,
                     h, hnew, zbuf, bar, out);
}